// Round 15
// baseline (22805.025 us; speedup 1.0000x reference)
//
#include <hip/hip_runtime.h>

#define HDIM 96
#define G4   384
#define LSEQ 32768
#define BATCH 8
#define TCH   1024
#define NCH   (LSEQ / TCH)

typedef float f2 __attribute__((ext_vector_type(2)));

__device__ __forceinline__ float sigm_(float x) {
    return __builtin_amdgcn_rcpf(1.f + __expf(-x));
}
__device__ __forceinline__ float tanh_(float x) {
    return fmaf(-2.f, __builtin_amdgcn_rcpf(1.f + __expf(2.f * x)), 1.f);
}

// Per-step barrier: LDS-only drain + s_barrier (global h stores drain once
// per chunk via __threadfence before the flag SIGNAL).
#define STEP_BARRIER() asm volatile("s_waitcnt lgkmcnt(0)\n\ts_barrier" ::: "memory")

// 8-lane butterfly sum on the VALU pipe (DPP).
#define DPPSTEP(v, CTRL) { \
    int t_ = __builtin_amdgcn_update_dpp(0, __float_as_int(v), CTRL, 0xF, 0xF, true); \
    v += __int_as_float(t_); }
#define RED8(v) DPPSTEP(v, 0xB1) DPPSTEP(v, 0x4E) DPPSTEP(v, 0x141)

#define PINF2(A,B,C) asm volatile("" : "+v"(A), "+v"(B), "+v"(C));
#define PIN4x3(A,B,C) asm volatile("" : \
  "+v"(A.x),"+v"(A.y),"+v"(A.z),"+v"(A.w), \
  "+v"(B.x),"+v"(B.y),"+v"(B.z),"+v"(B.w), \
  "+v"(C.x),"+v"(C.y),"+v"(C.z),"+v"(C.w));

// Thread owns all 4 gate rows of element e x cols [12s,12s+12), as 6 f2
// (packed col-pairs) per gate -> 24 v_pk_fma_f32 per step instead of 48 FMA.
#define WLOADPIN(W) \
    const f2* pI = reinterpret_cast<const f2*>((W) + (size_t)e        * HDIM + 12*s); \
    const f2* pF = reinterpret_cast<const f2*>((W) + (size_t)(96 + e) * HDIM + 12*s); \
    const f2* pG = reinterpret_cast<const f2*>((W) + (size_t)(192+ e) * HDIM + 12*s); \
    const f2* pO = reinterpret_cast<const f2*>((W) + (size_t)(288+ e) * HDIM + 12*s); \
    f2 wI0=pI[0],wI1=pI[1],wI2=pI[2],wI3=pI[3],wI4=pI[4],wI5=pI[5]; \
    f2 wF0=pF[0],wF1=pF[1],wF2=pF[2],wF3=pF[3],wF4=pF[4],wF5=pF[5]; \
    f2 wG0=pG[0],wG1=pG[1],wG2=pG[2],wG3=pG[3],wG4=pG[4],wG5=pG[5]; \
    f2 wO0=pO[0],wO1=pO[1],wO2=pO[2],wO3=pO[3],wO4=pO[4],wO5=pO[5]; \
    PINF2(wI0,wI1,wI2) PINF2(wI3,wI4,wI5) PINF2(wF0,wF1,wF2) PINF2(wF3,wF4,wF5) \
    PINF2(wG0,wG1,wG2) PINF2(wG3,wG4,wG5) PINF2(wO0,wO1,wO2) PINF2(wO3,wO4,wO5)

// Packed matvec for one gate: acc (f2) += w_k * h_k over 6 col-pairs.
#define MVP(acc, P) \
    acc = __builtin_elementwise_fma(P##0, hq0, acc); \
    acc = __builtin_elementwise_fma(P##1, hq1, acc); \
    acc = __builtin_elementwise_fma(P##2, hq2, acc); \
    acc = __builtin_elementwise_fma(P##3, hq3, acc); \
    acc = __builtin_elementwise_fma(P##4, hq4, acc); \
    acc = __builtin_elementwise_fma(P##5, hq5, acc);

// Load h segment (12 floats) from LDS as 3 b128, repack to 6 f2 (reg alias).
#define HLOAD(BASE) \
    const float4* hp_ = reinterpret_cast<const float4*>((BASE) + 12 * s); \
    float4 hv0 = hp_[0], hv1 = hp_[1], hv2 = hp_[2]; \
    f2 hq0 = {hv0.x, hv0.y}, hq1 = {hv0.z, hv0.w}; \
    f2 hq2 = {hv1.x, hv1.y}, hq3 = {hv1.z, hv1.w}; \
    f2 hq4 = {hv2.x, hv2.y}, hq5 = {hv2.z, hv2.w};

#define MV_ALL() \
    f2 aI = {0.f, 0.f}, aF = {0.f, 0.f}, aG = {0.f, 0.f}, aO = {0.f, 0.f}; \
    MVP(aI, wI) MVP(aF, wF) MVP(aG, wG) MVP(aO, wO) \
    float gi = aI.x + aI.y, gf = aF.x + aF.y, gg = aG.x + aG.y, go = aO.x + aO.y; \
    RED8(gi) RED8(gf) RED8(gg) RED8(go)

#define WAIT_GE(PTR, VAL) \
    while (__hip_atomic_load((PTR), __ATOMIC_ACQUIRE, __HIP_MEMORY_SCOPE_AGENT) < (VAL)) \
        __builtin_amdgcn_s_sleep(2);

#define SIGNAL(PTR, VAL) \
    __hip_atomic_store((PTR), (VAL), __ATOMIC_RELEASE, __HIP_MEMORY_SCOPE_AGENT);

__global__ void init_flags(int* flags) {
    if (threadIdx.x < 64) flags[threadIdx.x] = 0;
}

// ---------------------------------------------------------------------------
// 32 blocks, 4 roles (producer / xp / consumer / head), ring depth 2.
// Scan core: tid = e*8+s; one lgkm barrier/step; DPP butterfly; packed fp32
// matvec; h double-buffered in LDS; c redundant per-lane in registers.
// ---------------------------------------------------------------------------
__global__ void __launch_bounds__(768)
__attribute__((amdgpu_waves_per_eu(3, 3)))
lstm_pipe(const float* __restrict__ x,
          const float* __restrict__ Wih0, const float* __restrict__ Whh0, const float* __restrict__ b0v,
          const float* __restrict__ Wih1, const float* __restrict__ Whh1, const float* __restrict__ b1v,
          const float* __restrict__ h0v,  const float* __restrict__ c0v,
          const float* __restrict__ headw,const float* __restrict__ headb,
          float* __restrict__ h0buf, float* __restrict__ xpbuf, float* __restrict__ h1buf,
          int* flags, float* __restrict__ out)
{
    const int tid  = threadIdx.x;
    const int lane = tid & 63;
    const int e    = tid >> 3;     // element 0..95
    const int s    = tid & 7;      // 12-col segment 0..7
    const bool w0l = ((lane & 7) == 0);

    int* flag0 = flags;
    int* flag1 = flags + 8;
    int* flag2 = flags + 16;
    int* flag3 = flags + 24;

    __shared__ __align__(16) float hs[2 * HDIM];
    __shared__ __align__(16) float h_sh[32 * HDIM];
    __shared__ float ph_sh[G4];

    const int role = blockIdx.x >> 3;
    const int bidx = blockIdx.x & 7;

    if (role == 0) {
        // =================== producer: L0 scan ===================
        WLOADPIN(Whh0)
        const float wiI = Wih0[e],  wiF = Wih0[96+e],  wiG = Wih0[192+e],  wiO = Wih0[288+e];
        const float bbI = b0v[e],   bbF = b0v[96+e],   bbG = b0v[192+e],   bbO = b0v[288+e];

        float cU = c0v[e];
        if (w0l) hs[e] = h0v[e];
        __syncthreads();

        const float* xb  = x + (size_t)bidx * LSEQ;
        float*       hob = h0buf + (size_t)bidx * LSEQ * HDIM;
        float xt = xb[0];
        int rOff = 0;

#pragma unroll 1
        for (int t = 0; t < LSEQ; ++t) {
            int tn = (t + 1 < LSEQ) ? t + 1 : LSEQ - 1;
            float xnext = xb[tn];

            HLOAD(hs + rOff)
            MV_ALL()
            // bias + input term added ONCE, post-reduction (uniform per lane)
            gi += fmaf(wiI, xt, bbI);
            gf += fmaf(wiF, xt, bbF);
            gg += fmaf(wiG, xt, bbG);
            go += fmaf(wiO, xt, bbO);

            float si = sigm_(gi), sf = sigm_(gf), tg = tanh_(gg), so = sigm_(go);
            cU = fmaf(sf, cU, si * tg);
            float hN = so * tanh_(cU);

            if (w0l) {
                hs[(rOff ^ HDIM) + e] = hN;
                hob[(size_t)t * HDIM + e] = hN;
            }
            rOff ^= HDIM;
            xt = xnext;

            if (((t + 1) & (TCH - 1)) == 0) {
                __threadfence();          // drain global h stores for this chunk
                __syncthreads();
                if (tid == 0) SIGNAL(&flag0[bidx], (t + 1) / TCH)
            }
            STEP_BARRIER();
        }
    } else if (role == 1) {
        // =================== xp worker ===================
        const bool halfx = (tid >= G4);
        const int  g     = halfx ? tid - G4 : tid;
        const int  dstoff = (g % 96) * 4 + (g / 96);   // (e,gate) float4 layout
        const float4* Wxp = reinterpret_cast<const float4*>(Wih1 + (size_t)g * HDIM + (halfx ? 48 : 0));
        const float xbias = halfx ? 0.f : b1v[g];

        float4 q0=Wxp[0],q1=Wxp[1],q2=Wxp[2],q3=Wxp[3],q4=Wxp[4],q5=Wxp[5],
               q6=Wxp[6],q7=Wxp[7],q8=Wxp[8],q9=Wxp[9],q10=Wxp[10],q11=Wxp[11];
        PIN4x3(q0,q1,q2) PIN4x3(q3,q4,q5) PIN4x3(q6,q7,q8) PIN4x3(q9,q10,q11)

        const float* hsrcB = h0buf + (size_t)bidx * LSEQ * HDIM;

#pragma unroll 1
        for (int k = 0; k < NCH; ++k) {
            if (tid == 0) {
                WAIT_GE(&flag0[bidx], k + 1)
                if (k >= 2) WAIT_GE(&flag2[bidx], k - 1)
            }
            __syncthreads();
            __threadfence();

            const float* hsrc = hsrcB + (size_t)k * TCH * HDIM;
            float* xpd = xpbuf + ((size_t)bidx * 2 + (k & 1)) * TCH * G4;

#pragma unroll 1
            for (int t0 = 0; t0 < TCH; t0 += 32) {
                for (int i = tid; i < 32 * HDIM; i += 768)
                    h_sh[i] = hsrc[(size_t)t0 * HDIM + i];
                __syncthreads();
#pragma unroll 1
                for (int tt = 0; tt < 32; ++tt) {
                    const float4* h4 = reinterpret_cast<const float4*>(
                        h_sh + tt * HDIM + (halfx ? 48 : 0));
                    float a0 = xbias, a1 = 0.f, a2 = 0.f, a3 = 0.f;
                    float4 hv;
                    hv=h4[0];  a0=fmaf(q0.x, hv.x,a0); a1=fmaf(q0.y, hv.y,a1); a2=fmaf(q0.z, hv.z,a2); a3=fmaf(q0.w, hv.w,a3);
                    hv=h4[1];  a0=fmaf(q1.x, hv.x,a0); a1=fmaf(q1.y, hv.y,a1); a2=fmaf(q1.z, hv.z,a2); a3=fmaf(q1.w, hv.w,a3);
                    hv=h4[2];  a0=fmaf(q2.x, hv.x,a0); a1=fmaf(q2.y, hv.y,a1); a2=fmaf(q2.z, hv.z,a2); a3=fmaf(q2.w, hv.w,a3);
                    hv=h4[3];  a0=fmaf(q3.x, hv.x,a0); a1=fmaf(q3.y, hv.y,a1); a2=fmaf(q3.z, hv.z,a2); a3=fmaf(q3.w, hv.w,a3);
                    hv=h4[4];  a0=fmaf(q4.x, hv.x,a0); a1=fmaf(q4.y, hv.y,a1); a2=fmaf(q4.z, hv.z,a2); a3=fmaf(q4.w, hv.w,a3);
                    hv=h4[5];  a0=fmaf(q5.x, hv.x,a0); a1=fmaf(q5.y, hv.y,a1); a2=fmaf(q5.z, hv.z,a2); a3=fmaf(q5.w, hv.w,a3);
                    hv=h4[6];  a0=fmaf(q6.x, hv.x,a0); a1=fmaf(q6.y, hv.y,a1); a2=fmaf(q6.z, hv.z,a2); a3=fmaf(q6.w, hv.w,a3);
                    hv=h4[7];  a0=fmaf(q7.x, hv.x,a0); a1=fmaf(q7.y, hv.y,a1); a2=fmaf(q7.z, hv.z,a2); a3=fmaf(q7.w, hv.w,a3);
                    hv=h4[8];  a0=fmaf(q8.x, hv.x,a0); a1=fmaf(q8.y, hv.y,a1); a2=fmaf(q8.z, hv.z,a2); a3=fmaf(q8.w, hv.w,a3);
                    hv=h4[9];  a0=fmaf(q9.x, hv.x,a0); a1=fmaf(q9.y, hv.y,a1); a2=fmaf(q9.z, hv.z,a2); a3=fmaf(q9.w, hv.w,a3);
                    hv=h4[10]; a0=fmaf(q10.x,hv.x,a0); a1=fmaf(q10.y,hv.y,a1); a2=fmaf(q10.z,hv.z,a2); a3=fmaf(q10.w,hv.w,a3);
                    hv=h4[11]; a0=fmaf(q11.x,hv.x,a0); a1=fmaf(q11.y,hv.y,a1); a2=fmaf(q11.z,hv.z,a2); a3=fmaf(q11.w,hv.w,a3);
                    float part = (a0 + a1) + (a2 + a3);
                    if (halfx) ph_sh[g] = part;
                    __syncthreads();
                    if (!halfx) xpd[(size_t)(t0 + tt) * G4 + dstoff] = part + ph_sh[g];
                    __syncthreads();
                }
            }
            __threadfence();
            __syncthreads();
            if (tid == 0) SIGNAL(&flag1[bidx], k + 1)
        }
    } else if (role == 2) {
        // =================== consumer: L1 scan ===================
        WLOADPIN(Whh1)

        float cU = c0v[HDIM + e];
        if (w0l) hs[e] = h0v[HDIM + e];
        __syncthreads();
        int rOff = 0;

#pragma unroll 1
        for (int k = 0; k < NCH; ++k) {
            if (tid == 0) {
                WAIT_GE(&flag1[bidx], k + 1)
                if (k >= 2) WAIT_GE(&flag3[bidx], k - 1)
            }
            __syncthreads();
            __threadfence();

            const float4* xq  = reinterpret_cast<const float4*>(
                xpbuf + ((size_t)bidx * 2 + (k & 1)) * TCH * G4) + e;
            float* h1c = h1buf + ((size_t)bidx * 2 + (k & 1)) * TCH * HDIM;

            float4 xp4 = xq[0];

#pragma unroll 1
            for (int t = 0; t < TCH; ++t) {
                int tn = (t + 1 < TCH) ? t + 1 : TCH - 1;
                float4 xpn = xq[(size_t)tn * HDIM];

                HLOAD(hs + rOff)
                MV_ALL()
                // xp (bias folded) added ONCE, post-reduction
                gi += xp4.x; gf += xp4.y; gg += xp4.z; go += xp4.w;

                float si = sigm_(gi), sf = sigm_(gf), tg = tanh_(gg), so = sigm_(go);
                cU = fmaf(sf, cU, si * tg);
                float hN = so * tanh_(cU);

                if (w0l) {
                    hs[(rOff ^ HDIM) + e] = hN;
                    h1c[(size_t)t * HDIM + e] = hN;
                }
                rOff ^= HDIM;
                xp4 = xpn;
                STEP_BARRIER();
            }
            __threadfence();
            __syncthreads();
            if (tid == 0) SIGNAL(&flag2[bidx], k + 1)
        }
    } else {
        // =================== head ===================
        const float hb = headb[0];
        float4 wv[24];
#pragma unroll
        for (int j = 0; j < 24; ++j) wv[j] = reinterpret_cast<const float4*>(headw)[j];

#pragma unroll 1
        for (int k = 0; k < NCH; ++k) {
            if (tid == 0) WAIT_GE(&flag2[bidx], k + 1)
            __syncthreads();
            __threadfence();

            const float* h1c = h1buf + ((size_t)bidx * 2 + (k & 1)) * TCH * HDIM;
            for (int t = tid; t < TCH; t += 768) {
                const float4* hp = reinterpret_cast<const float4*>(h1c + (size_t)t * HDIM);
                float s2 = 0.f;
#pragma unroll
                for (int j = 0; j < 24; ++j) {
                    float4 a = hp[j], b = wv[j];
                    s2 = fmaf(a.x, b.x, s2); s2 = fmaf(a.y, b.y, s2);
                    s2 = fmaf(a.z, b.z, s2); s2 = fmaf(a.w, b.w, s2);
                }
                out[(size_t)bidx * LSEQ + (size_t)k * TCH + t] = s2 + hb;
            }
            __threadfence();
            __syncthreads();
            if (tid == 0) SIGNAL(&flag3[bidx], k + 1)
        }
    }
}

// ---------------------------------------------------------------------------
extern "C" void kernel_launch(void* const* d_in, const int* in_sizes, int n_in,
                              void* d_out, int out_size, void* d_ws, size_t ws_size,
                              hipStream_t stream)
{
    const float* x     = (const float*)d_in[0];
    const float* Wih0  = (const float*)d_in[1];
    const float* Whh0  = (const float*)d_in[2];
    const float* b0    = (const float*)d_in[3];
    const float* Wih1  = (const float*)d_in[4];
    const float* Whh1  = (const float*)d_in[5];
    const float* b1    = (const float*)d_in[6];
    const float* h0    = (const float*)d_in[7];
    const float* c0    = (const float*)d_in[8];
    const float* headw = (const float*)d_in[9];
    const float* headb = (const float*)d_in[10];
    float* out = (float*)d_out;

    char* ws = (char*)d_ws;
    const size_t h0bytes = (size_t)BATCH * LSEQ * HDIM * sizeof(float);    // 100.7 MB
    const size_t xpbytes = (size_t)BATCH * 2 * TCH * G4 * sizeof(float);   // 25.2 MB
    const size_t h1bytes = (size_t)BATCH * 2 * TCH * HDIM * sizeof(float); // 6.3 MB

    float* h0buf = (float*)ws;
    float* xpbuf = (float*)(ws + h0bytes);
    float* h1buf = (float*)(ws + h0bytes + xpbytes);
    int*   flags = (int*)  (ws + h0bytes + xpbytes + h1bytes);

    init_flags<<<1, 64, 0, stream>>>(flags);
    lstm_pipe<<<32, 768, 0, stream>>>(x, Wih0, Whh0, b0, Wih1, Whh1, b1,
                                      h0, c0, headw, headb,
                                      h0buf, xpbuf, h1buf, flags, out);
}

// Round 16
// 20222.394 us; speedup vs baseline: 1.1277x; 1.1277x over previous
//
#include <hip/hip_runtime.h>

#define HDIM 96
#define G4   384
#define LSEQ 32768
#define BATCH 8
#define TCH   1024
#define NCH   (LSEQ / TCH)

#define L2E  1.4426950408889634f   // log2(e)
#define C2E  2.8853900817779268f   // 2*log2(e)

// Activations on pre-scaled gates (gate' = gate * log2e):
//   sigm(x)  = rcp(1 + 2^(-x'))
//   tanh(x)  = 1 - 2*rcp(1 + 2^(2x'))      (x' scaled)
//   tanh(c)  = 1 - 2*rcp(1 + 2^(c*C2E))    (c in true scale)
__device__ __forceinline__ float sigmS(float xs) {
    return __builtin_amdgcn_rcpf(1.f + __builtin_amdgcn_exp2f(-xs));
}
__device__ __forceinline__ float tanhS(float xs) {
    return fmaf(-2.f, __builtin_amdgcn_rcpf(1.f + __builtin_amdgcn_exp2f(xs + xs)), 1.f);
}
__device__ __forceinline__ float tanhC(float c) {
    return fmaf(-2.f, __builtin_amdgcn_rcpf(1.f + __builtin_amdgcn_exp2f(c * C2E)), 1.f);
}

// Per-step barrier: LDS-only drain + s_barrier. Global stores/loads cross
// the barrier and drain either at their next use (vmcnt(N)) or at the
// chunk-boundary __threadfence + __syncthreads.
#define STEP_BARRIER() asm volatile("s_waitcnt lgkmcnt(0)\n\ts_barrier" ::: "memory")

// 8-lane butterfly sum on the VALU pipe (DPP).
#define DPPSTEP(v, CTRL) { \
    int t_ = __builtin_amdgcn_update_dpp(0, __float_as_int(v), CTRL, 0xF, 0xF, true); \
    v += __int_as_float(t_); }
#define RED8(v) DPPSTEP(v, 0xB1) DPPSTEP(v, 0x4E) DPPSTEP(v, 0x141)

#define PIN4x3(A,B,C) asm volatile("" : \
  "+v"(A.x),"+v"(A.y),"+v"(A.z),"+v"(A.w), \
  "+v"(B.x),"+v"(B.y),"+v"(B.z),"+v"(B.w), \
  "+v"(C.x),"+v"(C.y),"+v"(C.z),"+v"(C.w));

#define SC4(v) v.x *= L2E; v.y *= L2E; v.z *= L2E; v.w *= L2E;

// Thread owns all 4 gate rows of element e x cols [12s,12s+12); weights
// pre-scaled by log2e, then pinned.
#define WLOADPIN(W) \
    const float4* pI = reinterpret_cast<const float4*>((W) + (size_t)e        * HDIM + 12*s); \
    const float4* pF = reinterpret_cast<const float4*>((W) + (size_t)(96 + e) * HDIM + 12*s); \
    const float4* pG = reinterpret_cast<const float4*>((W) + (size_t)(192+ e) * HDIM + 12*s); \
    const float4* pO = reinterpret_cast<const float4*>((W) + (size_t)(288+ e) * HDIM + 12*s); \
    float4 wI0=pI[0], wI1=pI[1], wI2=pI[2]; \
    float4 wF0=pF[0], wF1=pF[1], wF2=pF[2]; \
    float4 wG0=pG[0], wG1=pG[1], wG2=pG[2]; \
    float4 wO0=pO[0], wO1=pO[1], wO2=pO[2]; \
    SC4(wI0) SC4(wI1) SC4(wI2) SC4(wF0) SC4(wF1) SC4(wF2) \
    SC4(wG0) SC4(wG1) SC4(wG2) SC4(wO0) SC4(wO1) SC4(wO2) \
    PIN4x3(wI0,wI1,wI2) PIN4x3(wF0,wF1,wF2) PIN4x3(wG0,wG1,wG2) PIN4x3(wO0,wO1,wO2)

#define MVK(n, hv) \
  gi=fmaf(wI##n.x,hv.x,gi); gi=fmaf(wI##n.y,hv.y,gi); gi=fmaf(wI##n.z,hv.z,gi); gi=fmaf(wI##n.w,hv.w,gi); \
  gf=fmaf(wF##n.x,hv.x,gf); gf=fmaf(wF##n.y,hv.y,gf); gf=fmaf(wF##n.z,hv.z,gf); gf=fmaf(wF##n.w,hv.w,gf); \
  gg=fmaf(wG##n.x,hv.x,gg); gg=fmaf(wG##n.y,hv.y,gg); gg=fmaf(wG##n.z,hv.z,gg); gg=fmaf(wG##n.w,hv.w,gg); \
  go=fmaf(wO##n.x,hv.x,go); go=fmaf(wO##n.y,hv.y,go); go=fmaf(wO##n.z,hv.z,go); go=fmaf(wO##n.w,hv.w,go);

#define WAIT_GE(PTR, VAL) \
    while (__hip_atomic_load((PTR), __ATOMIC_ACQUIRE, __HIP_MEMORY_SCOPE_AGENT) < (VAL)) \
        __builtin_amdgcn_s_sleep(2);

#define SIGNAL(PTR, VAL) \
    __hip_atomic_store((PTR), (VAL), __ATOMIC_RELEASE, __HIP_MEMORY_SCOPE_AGENT);

__global__ void init_flags(int* flags) {
    if (threadIdx.x < 64) flags[threadIdx.x] = 0;
}

// ---------------------------------------------------------------------------
// 32 blocks, 4 roles (producer / xp / consumer / head), ring depth 2.
// Scan core (round-13 structure): tid = e*8+s; DPP butterfly; h double-
// buffered in LDS; c redundant per-lane. Per-step barrier is lgkm-only so
// the producer's h stores and the consumer's xp prefetch loads overlap
// across steps; full drain once per chunk before the flag SIGNAL.
// ---------------------------------------------------------------------------
__global__ void __launch_bounds__(768)
__attribute__((amdgpu_waves_per_eu(3, 3)))
lstm_pipe(const float* __restrict__ x,
          const float* __restrict__ Wih0, const float* __restrict__ Whh0, const float* __restrict__ b0v,
          const float* __restrict__ Wih1, const float* __restrict__ Whh1, const float* __restrict__ b1v,
          const float* __restrict__ h0v,  const float* __restrict__ c0v,
          const float* __restrict__ headw,const float* __restrict__ headb,
          float* __restrict__ h0buf, float* __restrict__ xpbuf, float* __restrict__ h1buf,
          int* flags, float* __restrict__ out)
{
    const int tid  = threadIdx.x;
    const int lane = tid & 63;
    const int e    = tid >> 3;     // element 0..95
    const int s    = tid & 7;      // 12-col segment 0..7
    const bool w0l = ((lane & 7) == 0);

    int* flag0 = flags;
    int* flag1 = flags + 8;
    int* flag2 = flags + 16;
    int* flag3 = flags + 24;

    __shared__ __align__(16) float hs[2 * HDIM];
    __shared__ __align__(16) float h_sh[32 * HDIM];
    __shared__ float ph_sh[G4];

    const int role = blockIdx.x >> 3;
    const int bidx = blockIdx.x & 7;

    if (role == 0) {
        // =================== producer: L0 scan ===================
        WLOADPIN(Whh0)
        const float wiI = Wih0[e]     * L2E, wiF = Wih0[96+e]  * L2E,
                    wiG = Wih0[192+e] * L2E, wiO = Wih0[288+e] * L2E;
        const float bbI = b0v[e]      * L2E, bbF = b0v[96+e]   * L2E,
                    bbG = b0v[192+e]  * L2E, bbO = b0v[288+e]  * L2E;

        float cU = c0v[e];
        if (w0l) hs[e] = h0v[e];
        __syncthreads();

        const float* xb  = x + (size_t)bidx * LSEQ;
        float*       hob = h0buf + (size_t)bidx * LSEQ * HDIM;
        float xt = xb[0];
        int rOff = 0;

#pragma unroll 1
        for (int t = 0; t < LSEQ; ++t) {
            int tn = (t + 1 < LSEQ) ? t + 1 : LSEQ - 1;
            float xnext = xb[tn];

            const float4* hp = reinterpret_cast<const float4*>(hs + rOff + 12 * s);
            float4 hv0 = hp[0], hv1 = hp[1], hv2 = hp[2];

            float gi = 0.f, gf = 0.f, gg = 0.f, go = 0.f;
            MVK(0, hv0) MVK(1, hv1) MVK(2, hv2)
            RED8(gi) RED8(gf) RED8(gg) RED8(go)
            // bias + input term added ONCE, post-reduction (pre-scaled)
            gi += fmaf(wiI, xt, bbI);
            gf += fmaf(wiF, xt, bbF);
            gg += fmaf(wiG, xt, bbG);
            go += fmaf(wiO, xt, bbO);

            float si = sigmS(gi), sf = sigmS(gf), tg = tanhS(gg), so = sigmS(go);
            cU = fmaf(sf, cU, si * tg);
            float hN = so * tanhC(cU);

            if (w0l) {
                hs[(rOff ^ HDIM) + e] = hN;
                hob[(size_t)t * HDIM + e] = hN;
            }
            rOff ^= HDIM;
            xt = xnext;

            if (((t + 1) & (TCH - 1)) == 0) {
                __threadfence();          // drain global h stores for this chunk
                __syncthreads();
                if (tid == 0) SIGNAL(&flag0[bidx], (t + 1) / TCH)
            }
            STEP_BARRIER();
        }
    } else if (role == 1) {
        // =================== xp worker (output pre-scaled by log2e) ========
        const bool halfx = (tid >= G4);
        const int  g     = halfx ? tid - G4 : tid;
        const int  dstoff = (g % 96) * 4 + (g / 96);   // (e,gate) float4 layout
        const float4* Wxp = reinterpret_cast<const float4*>(Wih1 + (size_t)g * HDIM + (halfx ? 48 : 0));
        const float xbias = halfx ? 0.f : b1v[g] * L2E;

        float4 q0=Wxp[0],q1=Wxp[1],q2=Wxp[2],q3=Wxp[3],q4=Wxp[4],q5=Wxp[5],
               q6=Wxp[6],q7=Wxp[7],q8=Wxp[8],q9=Wxp[9],q10=Wxp[10],q11=Wxp[11];
        SC4(q0) SC4(q1) SC4(q2) SC4(q3) SC4(q4) SC4(q5)
        SC4(q6) SC4(q7) SC4(q8) SC4(q9) SC4(q10) SC4(q11)
        PIN4x3(q0,q1,q2) PIN4x3(q3,q4,q5) PIN4x3(q6,q7,q8) PIN4x3(q9,q10,q11)

        const float* hsrcB = h0buf + (size_t)bidx * LSEQ * HDIM;

#pragma unroll 1
        for (int k = 0; k < NCH; ++k) {
            if (tid == 0) {
                WAIT_GE(&flag0[bidx], k + 1)
                if (k >= 2) WAIT_GE(&flag2[bidx], k - 1)
            }
            __syncthreads();
            __threadfence();

            const float* hsrc = hsrcB + (size_t)k * TCH * HDIM;
            float* xpd = xpbuf + ((size_t)bidx * 2 + (k & 1)) * TCH * G4;

#pragma unroll 1
            for (int t0 = 0; t0 < TCH; t0 += 32) {
                for (int i = tid; i < 32 * HDIM; i += 768)
                    h_sh[i] = hsrc[(size_t)t0 * HDIM + i];
                __syncthreads();
#pragma unroll 1
                for (int tt = 0; tt < 32; ++tt) {
                    const float4* h4 = reinterpret_cast<const float4*>(
                        h_sh + tt * HDIM + (halfx ? 48 : 0));
                    float a0 = xbias, a1 = 0.f, a2 = 0.f, a3 = 0.f;
                    float4 hv;
                    hv=h4[0];  a0=fmaf(q0.x, hv.x,a0); a1=fmaf(q0.y, hv.y,a1); a2=fmaf(q0.z, hv.z,a2); a3=fmaf(q0.w, hv.w,a3);
                    hv=h4[1];  a0=fmaf(q1.x, hv.x,a0); a1=fmaf(q1.y, hv.y,a1); a2=fmaf(q1.z, hv.z,a2); a3=fmaf(q1.w, hv.w,a3);
                    hv=h4[2];  a0=fmaf(q2.x, hv.x,a0); a1=fmaf(q2.y, hv.y,a1); a2=fmaf(q2.z, hv.z,a2); a3=fmaf(q2.w, hv.w,a3);
                    hv=h4[3];  a0=fmaf(q3.x, hv.x,a0); a1=fmaf(q3.y, hv.y,a1); a2=fmaf(q3.z, hv.z,a2); a3=fmaf(q3.w, hv.w,a3);
                    hv=h4[4];  a0=fmaf(q4.x, hv.x,a0); a1=fmaf(q4.y, hv.y,a1); a2=fmaf(q4.z, hv.z,a2); a3=fmaf(q4.w, hv.w,a3);
                    hv=h4[5];  a0=fmaf(q5.x, hv.x,a0); a1=fmaf(q5.y, hv.y,a1); a2=fmaf(q5.z, hv.z,a2); a3=fmaf(q5.w, hv.w,a3);
                    hv=h4[6];  a0=fmaf(q6.x, hv.x,a0); a1=fmaf(q6.y, hv.y,a1); a2=fmaf(q6.z, hv.z,a2); a3=fmaf(q6.w, hv.w,a3);
                    hv=h4[7];  a0=fmaf(q7.x, hv.x,a0); a1=fmaf(q7.y, hv.y,a1); a2=fmaf(q7.z, hv.z,a2); a3=fmaf(q7.w, hv.w,a3);
                    hv=h4[8];  a0=fmaf(q8.x, hv.x,a0); a1=fmaf(q8.y, hv.y,a1); a2=fmaf(q8.z, hv.z,a2); a3=fmaf(q8.w, hv.w,a3);
                    hv=h4[9];  a0=fmaf(q9.x, hv.x,a0); a1=fmaf(q9.y, hv.y,a1); a2=fmaf(q9.z, hv.z,a2); a3=fmaf(q9.w, hv.w,a3);
                    hv=h4[10]; a0=fmaf(q10.x,hv.x,a0); a1=fmaf(q10.y,hv.y,a1); a2=fmaf(q10.z,hv.z,a2); a3=fmaf(q10.w,hv.w,a3);
                    hv=h4[11]; a0=fmaf(q11.x,hv.x,a0); a1=fmaf(q11.y,hv.y,a1); a2=fmaf(q11.z,hv.z,a2); a3=fmaf(q11.w,hv.w,a3);
                    float part = (a0 + a1) + (a2 + a3);
                    if (halfx) ph_sh[g] = part;
                    __syncthreads();
                    if (!halfx) xpd[(size_t)(t0 + tt) * G4 + dstoff] = part + ph_sh[g];
                    __syncthreads();
                }
            }
            __threadfence();
            __syncthreads();
            if (tid == 0) SIGNAL(&flag1[bidx], k + 1)
        }
    } else if (role == 2) {
        // =================== consumer: L1 scan ===================
        WLOADPIN(Whh1)

        float cU = c0v[HDIM + e];
        if (w0l) hs[e] = h0v[HDIM + e];
        __syncthreads();
        int rOff = 0;

#pragma unroll 1
        for (int k = 0; k < NCH; ++k) {
            if (tid == 0) {
                WAIT_GE(&flag1[bidx], k + 1)
                if (k >= 2) WAIT_GE(&flag3[bidx], k - 1)
            }
            __syncthreads();
            __threadfence();

            const float4* xq  = reinterpret_cast<const float4*>(
                xpbuf + ((size_t)bidx * 2 + (k & 1)) * TCH * G4) + e;
            float* h1c = h1buf + ((size_t)bidx * 2 + (k & 1)) * TCH * HDIM;

            float4 xp4 = xq[0];

#pragma unroll 1
            for (int t = 0; t < TCH; ++t) {
                int tn = (t + 1 < TCH) ? t + 1 : TCH - 1;
                float4 xpn = xq[(size_t)tn * HDIM];

                const float4* hp = reinterpret_cast<const float4*>(hs + rOff + 12 * s);
                float4 hv0 = hp[0], hv1 = hp[1], hv2 = hp[2];

                float gi = 0.f, gf = 0.f, gg = 0.f, go = 0.f;
                MVK(0, hv0) MVK(1, hv1) MVK(2, hv2)
                RED8(gi) RED8(gf) RED8(gg) RED8(go)
                // xp (bias folded, pre-scaled) added ONCE, post-reduction
                gi += xp4.x; gf += xp4.y; gg += xp4.z; go += xp4.w;

                float si = sigmS(gi), sf = sigmS(gf), tg = tanhS(gg), so = sigmS(go);
                cU = fmaf(sf, cU, si * tg);
                float hN = so * tanhC(cU);

                if (w0l) {
                    hs[(rOff ^ HDIM) + e] = hN;
                    h1c[(size_t)t * HDIM + e] = hN;
                }
                rOff ^= HDIM;
                xp4 = xpn;
                STEP_BARRIER();
            }
            __threadfence();
            __syncthreads();
            if (tid == 0) SIGNAL(&flag2[bidx], k + 1)
        }
    } else {
        // =================== head ===================
        const float hb = headb[0];
        float4 wv[24];
#pragma unroll
        for (int j = 0; j < 24; ++j) wv[j] = reinterpret_cast<const float4*>(headw)[j];

#pragma unroll 1
        for (int k = 0; k < NCH; ++k) {
            if (tid == 0) WAIT_GE(&flag2[bidx], k + 1)
            __syncthreads();
            __threadfence();

            const float* h1c = h1buf + ((size_t)bidx * 2 + (k & 1)) * TCH * HDIM;
            for (int t = tid; t < TCH; t += 768) {
                const float4* hp = reinterpret_cast<const float4*>(h1c + (size_t)t * HDIM);
                float s2 = 0.f;
#pragma unroll
                for (int j = 0; j < 24; ++j) {
                    float4 a = hp[j], b = wv[j];
                    s2 = fmaf(a.x, b.x, s2); s2 = fmaf(a.y, b.y, s2);
                    s2 = fmaf(a.z, b.z, s2); s2 = fmaf(a.w, b.w, s2);
                }
                out[(size_t)bidx * LSEQ + (size_t)k * TCH + t] = s2 + hb;
            }
            __threadfence();
            __syncthreads();
            if (tid == 0) SIGNAL(&flag3[bidx], k + 1)
        }
    }
}

// ---------------------------------------------------------------------------
extern "C" void kernel_launch(void* const* d_in, const int* in_sizes, int n_in,
                              void* d_out, int out_size, void* d_ws, size_t ws_size,
                              hipStream_t stream)
{
    const float* x     = (const float*)d_in[0];
    const float* Wih0  = (const float*)d_in[1];
    const float* Whh0  = (const float*)d_in[2];
    const float* b0    = (const float*)d_in[3];
    const float* Wih1  = (const float*)d_in[4];
    const float* Whh1  = (const float*)d_in[5];
    const float* b1    = (const float*)d_in[6];
    const float* h0    = (const float*)d_in[7];
    const float* c0    = (const float*)d_in[8];
    const float* headw = (const float*)d_in[9];
    const float* headb = (const float*)d_in[10];
    float* out = (float*)d_out;

    char* ws = (char*)d_ws;
    const size_t h0bytes = (size_t)BATCH * LSEQ * HDIM * sizeof(float);    // 100.7 MB
    const size_t xpbytes = (size_t)BATCH * 2 * TCH * G4 * sizeof(float);   // 25.2 MB
    const size_t h1bytes = (size_t)BATCH * 2 * TCH * HDIM * sizeof(float); // 6.3 MB

    float* h0buf = (float*)ws;
    float* xpbuf = (float*)(ws + h0bytes);
    float* h1buf = (float*)(ws + h0bytes + xpbytes);
    int*   flags = (int*)  (ws + h0bytes + xpbytes + h1bytes);

    init_flags<<<1, 64, 0, stream>>>(flags);
    lstm_pipe<<<32, 768, 0, stream>>>(x, Wih0, Whh0, b0, Wih1, Whh1, b1,
                                      h0, c0, headw, headb,
                                      h0buf, xpbuf, h1buf, flags, out);
}